// Round 19
// baseline (126.216 us; speedup 1.0000x reference)
//
#include <hip/hip_runtime.h>
#include <math.h>

#define T_LEN 1024
#define VV 512
#define BB 64
#define NB 16
#define ANG_STEP 0.006135923151542565f   // 2*pi/1024
#define FADE_S 487
#define FADE_E 537

typedef float v2f __attribute__((ext_vector_type(2)));   // native vec for nontemporal stores

__device__ constexpr int KB[NB] = {1,2,3,4,5,6,7,8,12,16,24,32,48,64,96,128};
// cos/sin(2*pi*k/1024) rotation-step constants (R1/R6-verified)
__device__ constexpr float CWT[NB] = {
    0.9999811753f, 0.9999247018f, 0.9998305818f, 0.9996988187f,
    0.9995294175f, 0.9993223846f, 0.9990777278f, 0.9987954562f,
    0.9972904567f, 0.9951847267f, 0.9891765100f, 0.9807852804f,
    0.9569403357f, 0.9238795325f, 0.8314696123f, 0.7071067812f};
__device__ constexpr float SWT[NB] = {
    0.0061358846f, 0.0122715383f, 0.0184067299f, 0.0245412285f,
    0.0306748032f, 0.0368072229f, 0.0429382569f, 0.0490676743f,
    0.0735645636f, 0.0980171403f, 0.1467304745f, 0.1950903220f,
    0.2902846773f, 0.3826834324f, 0.5555702330f, 0.7071067812f};

// ---------------- Fused kernel v5: rotation recurrence, zero LDS table ----------------
// grid (BB, 4) = 256 blocks (1/CU), block 512 = 8 waves. Wave w owns t-rows
// [w*128, w*128+128) of the block's 128-v slice (lane owns v0 = lane*2, VPT=2).
// cs generated IN REGISTERS by per-bin rotation recurrence (init sincos at trow):
// no LDS table -> the 41us/phase LDS-pipe bound (R17/R18) becomes 27us/phase VALU.
// Reduction via 16 KB scr in 4 rounds; H -> global; phase 2 re-reads x (L3-hot).
// Fade rows 487..536 are overwritten by k_fixup afterwards.
__global__ __launch_bounds__(512) void k_fused(const float* __restrict__ x,
                                               const float* __restrict__ ger,
                                               const float* __restrict__ gei,
                                               const float* __restrict__ glr,
                                               const float* __restrict__ gli,
                                               float* __restrict__ Hg,
                                               float* __restrict__ out) {
    const int b    = blockIdx.x;
    const int vc   = blockIdx.y;
    const int tid  = threadIdx.x;
    const int wave = tid >> 6;
    const int lane = tid & 63;

    __shared__ __align__(16) float scr[4 * 128 * 8];     // 16 KB reduction scratch

    const int trow = wave * 128;
    const int v0   = lane * 2;
    const float2* xrd = (const float2*)(x + ((size_t)b * T_LEN + trow) * VV + vc * 128) + lane;

    // ---- phase 1: per-wave DFT over its 128 t rows (recurrence cs) ----
    float ar0[NB], ai0[NB], ar1[NB], ai1[NB], c[NB], s[NB];
#pragma unroll
    for (int j = 0; j < NB; ++j) {
        ar0[j] = ai0[j] = ar1[j] = ai1[j] = 0.f;
        int n0 = (KB[j] * trow) & (T_LEN - 1);
        sincosf(ANG_STEP * (float)n0, &s[j], &c[j]);
    }

#define DFT_STEP(AV)                                            \
    do {                                                        \
        _Pragma("unroll")                                       \
        for (int j = 0; j < NB; ++j) {                          \
            ar0[j] = fmaf((AV).x, c[j], ar0[j]);                \
            ai0[j] = fmaf(-(AV).x, s[j], ai0[j]);               \
            ar1[j] = fmaf((AV).y, c[j], ar1[j]);                \
            ai1[j] = fmaf(-(AV).y, s[j], ai1[j]);               \
            float cn = fmaf(c[j], CWT[j], -(s[j] * SWT[j]));    \
            float sn = fmaf(s[j], CWT[j], c[j] * SWT[j]);       \
            c[j] = cn; s[j] = sn;                               \
        }                                                       \
    } while (0)

    {
        float2 a0 = xrd[(size_t)0 * 256];
        float2 a1 = xrd[(size_t)1 * 256];
        float2 a2 = xrd[(size_t)2 * 256];
        float2 a3 = xrd[(size_t)3 * 256];
#pragma unroll 1
        for (int i = 0; i < 124; i += 4) {
            float2 b0 = xrd[(size_t)(i + 4) * 256];
            float2 b1 = xrd[(size_t)(i + 5) * 256];
            float2 b2 = xrd[(size_t)(i + 6) * 256];
            float2 b3 = xrd[(size_t)(i + 7) * 256];
            DFT_STEP(a0); DFT_STEP(a1); DFT_STEP(a2); DFT_STEP(a3);
            a0 = b0; a1 = b1; a2 = b2; a3 = b3;
        }
        DFT_STEP(a0); DFT_STEP(a1); DFT_STEP(a2); DFT_STEP(a3);
    }
#undef DFT_STEP

    // ---- reduction: 4 rounds of 8 bins (re-lo, re-hi, im-lo, im-hi) ----
    float Xre_lo[2], Xre_hi[2], Xim_lo[2], Xim_hi[2];

#define RED_ROUND(SRC0, SRC1, JOFF, DST)                                   \
    do {                                                                   \
        if (wave < 4) {                                                    \
            _Pragma("unroll")                                              \
            for (int jj = 0; jj < 8; ++jj) {                               \
                scr[((size_t)wave * 128 + v0)     * 8 + jj] = SRC0[(JOFF) + jj]; \
                scr[((size_t)wave * 128 + v0 + 1) * 8 + jj] = SRC1[(JOFF) + jj]; \
            }                                                              \
        }                                                                  \
        __syncthreads();                                                   \
        if (wave >= 4) {                                                   \
            const int w2 = wave - 4;                                       \
            _Pragma("unroll")                                              \
            for (int jj = 0; jj < 8; ++jj) {                               \
                scr[((size_t)w2 * 128 + v0)     * 8 + jj] += SRC0[(JOFF) + jj]; \
                scr[((size_t)w2 * 128 + v0 + 1) * 8 + jj] += SRC1[(JOFF) + jj]; \
            }                                                              \
        }                                                                  \
        __syncthreads();                                                   \
        _Pragma("unroll")                                                  \
        for (int q = 0; q < 2; ++q) {                                      \
            const int cc = tid * 2 + q;                                    \
            const int vq = cc >> 3, jq = cc & 7;                           \
            DST[q] = scr[((size_t)0 * 128 + vq) * 8 + jq]                  \
                   + scr[((size_t)1 * 128 + vq) * 8 + jq]                  \
                   + scr[((size_t)2 * 128 + vq) * 8 + jq]                  \
                   + scr[((size_t)3 * 128 + vq) * 8 + jq];                 \
        }                                                                  \
        __syncthreads();                                                   \
    } while (0)

    RED_ROUND(ar0, ar1, 0, Xre_lo);
    RED_ROUND(ar0, ar1, 8, Xre_hi);
    RED_ROUND(ai0, ai1, 0, Xim_lo);
    RED_ROUND(ai0, ai1, 8, Xim_hi);
#undef RED_ROUND

    // ---- H compute -> global (4 cells per thread; R18-proven mapping) ----
    const float scale = 2.0f / (float)T_LEN;
    {
        float* hg = Hg + (size_t)b * 64 * VV;
#pragma unroll
        for (int q = 0; q < 2; ++q) {
            const int cc = tid * 2 + q;
            const int vq = cc >> 3;
            const int vg = vc * 128 + vq;
#pragma unroll
            for (int half = 0; half < 2; ++half) {
                const int jq = (cc & 7) + half * 8;
                const float Xr = half ? Xre_hi[q] : Xre_lo[q];
                const float Xi = half ? Xim_hi[q] : Xim_lo[q];
                float er = ger[vg * NB + jq], ei = gei[vg * NB + jq];
                float lr = glr[vg * NB + jq], li = gli[vg * NB + jq];
                float here  = (Xr * er - Xi * ei) * scale;
                float heimN = -(Xr * ei + Xi * er) * scale;
                float hlre  = (Xr * lr - Xi * li) * scale;
                float hlimN = -(Xr * li + Xi * lr) * scale;
                hg[(size_t)jq * VV + vg]        = here;
                hg[(size_t)(16 + jq) * VV + vg] = heimN;
                hg[(size_t)(32 + jq) * VV + vg] = hlre;
                hg[(size_t)(48 + jq) * VV + vg] = hlimN;
            }
        }
    }
    __syncthreads();   // Hg writes visible block-wide before phase-2 reads

    // ---- phase 2: apply (He waves 0..3, Hl waves 4..7), recurrence cs ----
    float hr0[NB], hi0[NB], hr1[NB], hi1[NB];
    {
        const int qb = (wave < 4) ? 0 : 32;
        const float* hgr = Hg + (size_t)b * 64 * VV + vc * 128;
#pragma unroll
        for (int j = 0; j < NB; ++j) {
            hr0[j] = hgr[(size_t)(qb + j) * VV + v0];
            hr1[j] = hgr[(size_t)(qb + j) * VV + v0 + 1];
            hi0[j] = hgr[(size_t)(qb + 16 + j) * VV + v0];
            hi1[j] = hgr[(size_t)(qb + 16 + j) * VV + v0 + 1];
        }
        // re-init recurrence at trow
#pragma unroll
        for (int j = 0; j < NB; ++j) {
            int n0 = (KB[j] * trow) & (T_LEN - 1);
            sincosf(ANG_STEP * (float)n0, &s[j], &c[j]);
        }
    }

    v2f* ow = (v2f*)(out + ((size_t)b * T_LEN + trow) * VV + vc * 128) + lane;

#define APPLY_STEP(TT, AV)                                      \
    do {                                                        \
        float s0 = 0.f, s1 = 0.f;                               \
        _Pragma("unroll")                                       \
        for (int j = 0; j < NB; ++j) {                          \
            s0 = fmaf(hr0[j], c[j], s0);                        \
            s0 = fmaf(hi0[j], s[j], s0);                        \
            s1 = fmaf(hr1[j], c[j], s1);                        \
            s1 = fmaf(hi1[j], s[j], s1);                        \
            float cn = fmaf(c[j], CWT[j], -(s[j] * SWT[j]));    \
            float sn = fmaf(s[j], CWT[j], c[j] * SWT[j]);       \
            c[j] = cn; s[j] = sn;                               \
        }                                                       \
        v2f ov; ov.x = (AV).x + s0; ov.y = (AV).y + s1;         \
        __builtin_nontemporal_store(ov, &ow[(size_t)(TT) * 256]); \
    } while (0)

    {
        float2 a0 = xrd[(size_t)0 * 256];
        float2 a1 = xrd[(size_t)1 * 256];
        float2 a2 = xrd[(size_t)2 * 256];
        float2 a3 = xrd[(size_t)3 * 256];
#pragma unroll 1
        for (int i = 0; i < 124; i += 4) {
            float2 b0 = xrd[(size_t)(i + 4) * 256];
            float2 b1 = xrd[(size_t)(i + 5) * 256];
            float2 b2 = xrd[(size_t)(i + 6) * 256];
            float2 b3 = xrd[(size_t)(i + 7) * 256];
            APPLY_STEP(i + 0, a0); APPLY_STEP(i + 1, a1);
            APPLY_STEP(i + 2, a2); APPLY_STEP(i + 3, a3);
            a0 = b0; a1 = b1; a2 = b2; a3 = b3;
        }
        APPLY_STEP(124, a0); APPLY_STEP(125, a1);
        APPLY_STEP(126, a2); APPLY_STEP(127, a3);
    }
#undef APPLY_STEP
}

// ---------------- Fade fixup, rows 487..536 only (exact dual-H crossfade) ----------------
// grid (BB, 2), block 512, thread owns v = tid.
__global__ __launch_bounds__(512) void k_fixup(const float* __restrict__ x,
                                               const float* __restrict__ H,
                                               float* __restrict__ out) {
    const int b   = blockIdx.x;
    const int tz  = blockIdx.y;
    const int tid = threadIdx.x;
    const int ts  = tz ? 512 : FADE_S;
    const int te  = tz ? FADE_E : 512;
    const int nt  = te - ts;                   // 25 rows each

    __shared__ float2 tab[32][NB];
    for (int i = tid; i < nt * NB; i += 512) {
        int t = i >> 4, j = i & 15;
        int idx = (KB[j] * (ts + t)) & (T_LEN - 1);
        float ss, cc; sincosf(ANG_STEP * (float)idx, &ss, &cc);
        tab[t][j] = make_float2(cc, ss);
    }

    float er[NB], ei[NB], lr[NB], li[NB];
    const float* hp = H + (size_t)b * 64 * VV + tid;
#pragma unroll
    for (int j = 0; j < NB; ++j) {
        er[j] = hp[(size_t)j        * VV];
        ei[j] = hp[(size_t)(16 + j) * VV];
        lr[j] = hp[(size_t)(32 + j) * VV];
        li[j] = hp[(size_t)(48 + j) * VV];
    }
    __syncthreads();

    const float* xrd = x + ((size_t)b * T_LEN + ts) * VV + tid;
    float*       ow  = out + ((size_t)b * T_LEN + ts) * VV + tid;

    for (int t = 0; t < nt; ++t) {
        float av = xrd[(size_t)t * VV];
        const int tg = ts + t;
        float se = 0.f, sl = 0.f;
#pragma unroll
        for (int j = 0; j < NB; ++j) {
            float2 cs = tab[t][j];
            se = fmaf(er[j], cs.x, se); se = fmaf(ei[j], cs.y, se);
            sl = fmaf(lr[j], cs.x, sl); sl = fmaf(li[j], cs.y, sl);
        }
        float w = 1.0f - (float)(tg - FADE_S) * (1.0f / 50.0f);
        ow[(size_t)t * VV] = av + fmaf(w, se - sl, sl);
    }
}

extern "C" void kernel_launch(void* const* d_in, const int* in_sizes, int n_in,
                              void* d_out, int out_size, void* d_ws, size_t ws_size,
                              hipStream_t stream) {
    (void)in_sizes; (void)n_in; (void)out_size; (void)ws_size;
    const float* x   = (const float*)d_in[0];
    const float* ger = (const float*)d_in[1];
    const float* gei = (const float*)d_in[2];
    const float* glr = (const float*)d_in[3];
    const float* gli = (const float*)d_in[4];
    float* out = (float*)d_out;

    float* Hg = (float*)d_ws;    // BB*64*VV floats = 8.4 MB

    k_fused<<<dim3(BB, 4), 512, 0, stream>>>(x, ger, gei, glr, gli, Hg, out);
    k_fixup<<<dim3(BB, 2), 512, 0, stream>>>(x, Hg, out);
}